// Round 9
// baseline (471.755 us; speedup 1.0000x reference)
//
#include <hip/hip_runtime.h>
#include <hip/hip_bf16.h>
#include <math.h>

#define BDIM 2
#define TSEQ 2048
#define CDIM 1024
#define HNUM 16
#define NROW (BDIM*TSEQ)
#define AST 72   // attn LDS row stride

typedef __attribute__((ext_vector_type(8))) short bf16x8_t;
typedef __attribute__((ext_vector_type(4))) float f32x4_t;

__device__ inline float bf2f(__hip_bfloat16 h) { return __bfloat162float(h); }

__device__ inline void unpack8(uint4 u, float* f) {
  unsigned v[4] = {u.x, u.y, u.z, u.w};
  #pragma unroll
  for (int i = 0; i < 4; ++i) {
    union { unsigned u2; float f2; } a, b;
    a.u2 = v[i] << 16;
    b.u2 = v[i] & 0xffff0000u;
    f[2*i]   = a.f2;
    f[2*i+1] = b.f2;
  }
}

// async global->LDS, 16B per lane; LDS dest = uniform base + lane*16
__device__ inline void gload16(const void* g, void* l) {
  __builtin_amdgcn_global_load_lds(
      (const __attribute__((address_space(1))) void*)g,
      (__attribute__((address_space(3))) void*)l, 16, 0, 0);
}

template<int N> __device__ inline void waitcnt_vm() {
  asm volatile("s_waitcnt vmcnt(%0)" :: "i"(N) : "memory");
}

__global__ __launch_bounds__(256) void zero32_kernel(float* p, int n) {
  int i = blockIdx.x * 256 + threadIdx.x;
  if (i < n) p[i] = 0.f;
}

// fp32 [K][N] -> bf16 [N][K] transpose-convert via LDS tile
__device__ inline void convT_body(const float* __restrict__ src,
    __hip_bfloat16* __restrict__ dst, int K, int N, int bx, int by)
{
  __shared__ float tile[32][33];
  const int k0 = bx * 32, n0 = by * 32;
  const int tr  = threadIdx.x >> 3;
  const int tc4 = (threadIdx.x & 7) * 4;
  float4 v = *(const float4*)(src + (size_t)(k0 + tr) * N + n0 + tc4);
  tile[tr][tc4+0] = v.x; tile[tr][tc4+1] = v.y;
  tile[tr][tc4+2] = v.z; tile[tr][tc4+3] = v.w;
  __syncthreads();
  union { ushort4 u; __hip_bfloat16 h[4]; } o;
  #pragma unroll
  for (int j = 0; j < 4; ++j) o.h[j] = __float2bfloat16(tile[tc4+j][tr]);
  *(ushort4*)(dst + (size_t)(n0 + tr) * K + k0 + tc4) = o.u;
}

__global__ __launch_bounds__(256) void convT_kernel(const float* __restrict__ src,
    __hip_bfloat16* __restrict__ dst, int K, int N)
{
  convT_body(src, dst, K, N, blockIdx.x, blockIdx.y);
}

// phase-2: both weight conversions in one launch
__global__ __launch_bounds__(256) void convT2_kernel(const float* __restrict__ s1,
    __hip_bfloat16* __restrict__ d1, const float* __restrict__ s2,
    __hip_bfloat16* __restrict__ d2)
{
  int g = blockIdx.x;
  if (g < 4096) {
    convT_body(s1, d1, 1024, 4096, g & 31, g >> 5);
  } else {
    g -= 4096;
    convT_body(s2, d2, 4096, 1024, g & 127, g >> 7);
  }
}

__device__ inline void blk_reduce3(float& a, float& b, float& c, float* red) {
  const int lane = threadIdx.x & 63, wv = threadIdx.x >> 6;
  #pragma unroll
  for (int off = 32; off; off >>= 1) {
    a += __shfl_xor(a, off); b += __shfl_xor(b, off); c += __shfl_xor(c, off);
  }
  if (lane == 0) { red[wv] = a; red[4+wv] = b; red[8+wv] = c; }
  __syncthreads();
  a = red[0]+red[1]+red[2]+red[3];
  b = red[4]+red[5]+red[6]+red[7];
  c = red[8]+red[9]+red[10]+red[11];
}

// ---------------- LayerNorm: fp32 in, fp32 w/b, bf16 out ----------------
__global__ __launch_bounds__(256) void ln_kernel(const float* __restrict__ x,
    const float* __restrict__ w, const float* __restrict__ b,
    __hip_bfloat16* __restrict__ out)
{
  const int row = blockIdx.x;
  const size_t base = (size_t)row * CDIM;
  const int lane = threadIdx.x & 63, wv = threadIdx.x >> 6;
  float v[4]; float s = 0.f, s2 = 0.f;
  #pragma unroll
  for (int k = 0; k < 4; ++k) {
    int d = threadIdx.x + k*256;
    float xe = x[base + d];
    v[k] = xe; s += xe; s2 += xe*xe;
  }
  __shared__ float red[8];
  #pragma unroll
  for (int off = 32; off; off >>= 1) { s += __shfl_xor(s, off); s2 += __shfl_xor(s2, off); }
  if (lane == 0) { red[wv] = s; red[4+wv] = s2; }
  __syncthreads();
  s  = red[0]+red[1]+red[2]+red[3];
  s2 = red[4]+red[5]+red[6]+red[7];
  float mu = s * (1.0f/CDIM);
  float var = s2 * (1.0f/CDIM) - mu*mu;
  float rstd = rsqrtf(fmaxf(var, 0.f) + 1e-5f);
  #pragma unroll
  for (int k = 0; k < 4; ++k) {
    int d = threadIdx.x + k*256;
    out[base + d] = __float2bfloat16((v[k]-mu)*rstd*w[d] + b[d]);
  }
}

// ---------------- scalmix1: logmap coeffs + xt[r] = P*xn[r] + Q*xn[r-1] ----------------
__global__ __launch_bounds__(256) void scalmix1_kernel(const __hip_bfloat16* __restrict__ xn,
                                                       __hip_bfloat16* __restrict__ xt)
{
  const int row = blockIdx.x;
  const bool has = (row & (TSEQ-1)) != 0;
  const __hip_bfloat16* u  = xn + (size_t)row * CDIM;
  const __hip_bfloat16* xp = xn + (size_t)(has ? row-1 : row) * CDIM;
  float ue[4], xe[4];
  float sxx = 0.f, suu = 0.f, sxu = 0.f;
  #pragma unroll
  for (int k = 0; k < 4; ++k) {
    int d = threadIdx.x + k*256;
    ue[k] = bf2f(u[d]);
    xe[k] = has ? bf2f(xp[d]) : 0.f;
    sxx += xe[k]*xe[k]; suu += ue[k]*ue[k]; sxu += xe[k]*ue[k];
  }
  __shared__ float red[12];
  blk_reduce3(sxx, suu, sxu, red);
  float den = 1.f - 2.f*sxu + sxx*suu;
  float inv = 1.f / fmaxf(den, 1e-30f);
  float cb = 1.f - sxx;
  float ca = 1.f - 2.f*sxu + suu;
  float mm = inv*inv*(cb*cb*suu - 2.f*ca*cb*sxu + ca*ca*sxx);
  float mn = sqrtf(fmaxf(mm, 0.f));
  float arg = fminf(sqrtf(mn), 0.999f);
  float fac = (1.f + sxx) * atanhf(arg) / fmaxf(mn, 1e-30f);
  float P = fac*cb*inv;
  float Q = has ? -fac*ca*inv : 0.f;
  #pragma unroll
  for (int k = 0; k < 4; ++k) {
    int d = threadIdx.x + k*256;
    xt[(size_t)row*CDIM + d] = __float2bfloat16(P*ue[k] + Q*xe[k]);
  }
}

// ---------------- partial-slot pointer helper (1152 slots x 8192 elem) ----------------
__device__ inline const __hip_bfloat16* slot_ptrc(const __hip_bfloat16* p0,
                                                  const __hip_bfloat16* p1, int s) {
  return (s < 1024) ? p0 + (size_t)s*8192 : p1 + (size_t)(s-1024)*8192;
}
__device__ inline __hip_bfloat16* slot_ptr(__hip_bfloat16* p0, __hip_bfloat16* p1, int s) {
  return (s < 1024) ? p0 + (size_t)s*8192 : p1 + (size_t)(s-1024)*8192;
}

// ---------------- scalmix2 (+ inline partial combine): e[r] = S*y[r] + R*xn[r-1] ----------------
__global__ __launch_bounds__(256) void scalmix2_kernel(const __hip_bfloat16* __restrict__ xn,
    const __hip_bfloat16* __restrict__ y,
    const __hip_bfloat16* __restrict__ pO0, const __hip_bfloat16* __restrict__ pO1,
    const float2* __restrict__ ml,
    __hip_bfloat16* __restrict__ e)
{
  const int row = blockIdx.x;
  const int b = row >> 11, t = row & 2047;
  const int qt2 = t >> 7, q = t & 127;
  const bool has = (t != 0);
  const __hip_bfloat16* xp = xn + (size_t)(has ? row-1 : row) * CDIM;
  float ve[4], xe[4];

  if (qt2 < 4) {
    const __hip_bfloat16* vr = y + (size_t)row * CDIM;
    #pragma unroll
    for (int k = 0; k < 4; ++k) ve[k] = bf2f(vr[threadIdx.x + k*256]);
  } else {
    const int nch = (qt2 >= 12) ? 4 : (qt2 >= 8) ? 3 : 2;
    const int off = (qt2 >= 12) ? 20 + (qt2-12)*4 : (qt2 >= 8) ? 8 + (qt2-8)*3 : (qt2-4)*2;
    #pragma unroll
    for (int k = 0; k < 4; ++k) {
      int d = threadIdx.x + k*256;
      int h = d >> 6, dd = d & 63;
      int s0 = (b*16 + h)*36 + off;
      float mi[4], li[4], M = -1e30f;
      #pragma unroll
      for (int i = 0; i < 4; ++i) if (i < nch) {
        float2 tt = ml[(size_t)(s0+i)*128 + q];
        mi[i] = tt.x; li[i] = tt.y; M = fmaxf(M, tt.x);
      }
      int base = (q>>4)*1024 + (dd>>4)*256 + (q&3)*64 + ((q>>2)&3)*16 + (dd&15);
      float denom = 0.f, acc = 0.f;
      #pragma unroll
      for (int i = 0; i < 4; ++i) if (i < nch) {
        float w = __expf(mi[i] - M);
        denom += li[i]*w;
        acc += w * bf2f(slot_ptrc(pO0, pO1, s0+i)[base]);
      }
      ve[k] = acc / denom;
    }
  }

  float sxx = 0.f, svv = 0.f, sxv = 0.f;
  #pragma unroll
  for (int k = 0; k < 4; ++k) {
    int d = threadIdx.x + k*256;
    xe[k] = has ? bf2f(xp[d]) : 0.f;
    sxx += xe[k]*xe[k]; svv += ve[k]*ve[k]; sxv += xe[k]*ve[k];
  }
  __shared__ float red[12];
  blk_reduce3(sxx, svv, sxv, red);
  float lam = 2.f / (1.f + sxx);
  float vn  = sqrtf(fmaxf(svv, 1e-30f));
  float th  = tanhf(vn * sqrtf(0.5f*lam));
  float s   = th / vn;
  float yn2 = th*th;
  float ip  = s * sxv;
  float den = 1.f + 2.f*ip + sxx*yn2;
  float inv = 1.f / fmaxf(den, 1e-30f);
  float S = (1.f - sxx)*s*inv;
  float R = has ? (1.f + 2.f*ip + yn2)*inv : 0.f;
  #pragma unroll
  for (int k = 0; k < 4; ++k) {
    int d = threadIdx.x + k*256;
    e[(size_t)row*CDIM + d] = __float2bfloat16(S*ve[k] + R*xe[k]);
  }
}

// ---------------- MFMA GEMM: NB-buffer counted-vmcnt pipeline ----------------
// A [M][K], Bt [N][K], both bf16. Per iter: wait vmcnt -> barrier -> stage(t+NB-1)
// -> compute(t). Loads never drained to 0 inside the loop.
// MODE 0: bf16 out = acc + bias
// MODE 1: f32  out = acc + bias + res   (in-place ok)
// MODE 2: bf16 out = gelu(acc + bias)
// MODE 7: f32  out = acc + res          (in-place ok)
template<int BM, int BN, int NB, int MODE>
__global__ __launch_bounds__(256) void gemmT_kernel(
    const __hip_bfloat16* __restrict__ A, int lda,
    const __hip_bfloat16* __restrict__ Bt, int ldb,
    const float* __restrict__ bias,
    const float* __restrict__ res,
    void* __restrict__ outp,
    int N, int K)
{
  __shared__ __align__(16) __hip_bfloat16 As[NB][BM*32];
  __shared__ __align__(16) __hip_bfloat16 Bs[NB][BN*32];
  const int bm = blockIdx.x, bn = blockIdx.y;
  const int tid = threadIdx.x, lane = tid & 63, wv = tid >> 6;
  constexpr int FM = BM/32, FN = BN/32;
  const int wm = (wv >> 1) * (BM/2), wn = (wv & 1) * (BN/2);
  f32x4_t acc[FM][FN];
  #pragma unroll
  for (int m = 0; m < FM; ++m)
    #pragma unroll
    for (int n = 0; n < FN; ++n) acc[m][n] = (f32x4_t){0.f,0.f,0.f,0.f};

  const int fr = lane & 15, quad = lane >> 4, q8 = quad * 8;
  const int srow = lane >> 2, scol = (lane & 3) * 8;
  constexpr int SA = BM/16, SB = BN/16;
  constexpr int L = SA/4 + SB/4;   // per-wave loads per tile
  const __hip_bfloat16* Ag = A  + (size_t)(bm*BM + srow)*lda + scol;
  const __hip_bfloat16* Bg = Bt + (size_t)(bn*BN + srow)*ldb + scol;

  const int nk = K/32;

  // prologue: stage tiles 0..NB-2 into buffers 0..NB-2
  #pragma unroll
  for (int pt = 0; pt < NB-1; ++pt) {
    #pragma unroll
    for (int i = 0; i < SA/4; ++i) {
      int s = wv*(SA/4) + i;
      gload16(Ag + (size_t)(s*16)*lda + pt*32, &As[pt][s*512]);
    }
    #pragma unroll
    for (int i = 0; i < SB/4; ++i) {
      int s = wv*(SB/4) + i;
      gload16(Bg + (size_t)(s*16)*ldb + pt*32, &Bs[pt][s*512]);
    }
  }

  int b0 = 0;
  for (int t = 0; t < nk; ++t) {
    const int rem = nk - 1 - t;   // tiles staged beyond t (in flight)
    if (rem >= NB-2) waitcnt_vm<(NB-2)*L>();
    else if (NB >= 4 && rem >= 1) waitcnt_vm<L>();
    else waitcnt_vm<0>();
    __builtin_amdgcn_s_barrier();
    __builtin_amdgcn_sched_barrier(0);
    if (t + NB - 1 < nk) {
      const int k0 = (t+NB-1)*32;
      int bw = b0 + (NB-1); if (bw >= NB) bw -= NB;
      #pragma unroll
      for (int i = 0; i < SA/4; ++i) {
        int s = wv*(SA/4) + i;
        gload16(Ag + (size_t)(s*16)*lda + k0, &As[bw][s*512]);
      }
      #pragma unroll
      for (int i = 0; i < SB/4; ++i) {
        int s = wv*(SB/4) + i;
        gload16(Bg + (size_t)(s*16)*ldb + k0, &Bs[bw][s*512]);
      }
    }
    bf16x8_t af[FM], bfr[FN];
    #pragma unroll
    for (int m = 0; m < FM; ++m) af[m]  = *(const bf16x8_t*)&As[b0][(wm + m*16 + fr)*32 + q8];
    #pragma unroll
    for (int n = 0; n < FN; ++n) bfr[n] = *(const bf16x8_t*)&Bs[b0][(wn + n*16 + fr)*32 + q8];
    __builtin_amdgcn_s_setprio(1);
    #pragma unroll
    for (int m = 0; m < FM; ++m)
      #pragma unroll
      for (int n = 0; n < FN; ++n)
        acc[m][n] = __builtin_amdgcn_mfma_f32_16x16x32_bf16(af[m], bfr[n], acc[m][n], 0, 0, 0);
    __builtin_amdgcn_s_setprio(0);
    ++b0; if (b0 == NB) b0 = 0;
  }

  #pragma unroll
  for (int m = 0; m < FM; ++m)
  #pragma unroll
  for (int n = 0; n < FN; ++n)
  #pragma unroll
  for (int r = 0; r < 4; ++r) {
    int row = bm*BM + wm + m*16 + quad*4 + r;
    int col = bn*BN + wn + n*16 + fr;
    size_t idx = (size_t)row * N + col;
    float v = acc[m][n][r];
    if (MODE == 0) {
      v += bias[col];
      ((__hip_bfloat16*)outp)[idx] = __float2bfloat16(v);
    } else if (MODE == 1) {
      v += bias[col] + res[idx];
      ((float*)outp)[idx] = v;
    } else if (MODE == 2) {
      v += bias[col];
      v = 0.5f * v * (1.0f + erff(v * 0.70710678118654752f));
      ((__hip_bfloat16*)outp)[idx] = __float2bfloat16(v);
    } else {
      v += res[idx];
      ((float*)outp)[idx] = v;
    }
  }
}

// ---------------- MFMA flash attention: 128 q-rows/block, 8 waves, KV-split ----------------
__global__ __launch_bounds__(512) void attn_kernel(const __hip_bfloat16* __restrict__ qkv,
                                                   __hip_bfloat16* __restrict__ y,
                                                   __hip_bfloat16* __restrict__ pO0,
                                                   __hip_bfloat16* __restrict__ pO1,
                                                   float2* __restrict__ ml)
{
  const int wid = blockIdx.x;
  int qt2, ci;
  if (wid < 16)      { qt2 = 15 - (wid >> 2); ci = wid & 3; }
  else if (wid < 28) { int w = wid - 16; qt2 = 11 - w/3; ci = w - (11 - qt2)*3; }
  else if (wid < 36) { int w = wid - 28; qt2 = 7 - (w >> 1); ci = w & 1; }
  else               { qt2 = 39 - wid; ci = 0; }
  const int tb = ci * 8;
  const int te = min(tb + 8, 2*qt2 + 2);
  const bool direct = (qt2 < 4);

  const int pair = blockIdx.y;
  const int b  = pair >> 4;
  const int h  = pair & 15;
  const int tid = threadIdx.x;
  const int lane = tid & 63;
  const int wv = tid >> 6;          // 0..7
  const int t0 = qt2 * 128;

  __shared__ __align__(16) __hip_bfloat16 Ks[64*AST];
  __shared__ __align__(16) __hip_bfloat16 Vt[64*AST];
  __shared__ __align__(16) __hip_bfloat16 Ps[8][16*AST];

  const int colq = lane & 15, quad = lane >> 4;
  const int q8 = quad * 8;

  const __hip_bfloat16* qp = qkv + ((size_t)(b*TSEQ + t0 + wv*16 + colq))*(3*CDIM) + h*64;
  const bf16x8_t qa0 = *(const bf16x8_t*)(qp + q8);
  const bf16x8_t qa1 = *(const bf16x8_t*)(qp + 32 + q8);

  f32x4_t oacc[4];
  #pragma unroll
  for (int tn = 0; tn < 4; ++tn) oacc[tn] = (f32x4_t){0.f,0.f,0.f,0.f};
  float mr[4] = {-1e30f,-1e30f,-1e30f,-1e30f};
  float lr[4] = {0.f,0.f,0.f,0.f};

  const int jr = tid >> 3;
  const int sg = (tid & 7) * 8;
  const size_t kvbase = ((size_t)(b*TSEQ))*(3*CDIM) + h*64;

  uint4 ck, cv;
  {
    const __hip_bfloat16* kp = qkv + kvbase + (size_t)(tb*64 + jr)*(3*CDIM) + CDIM + sg;
    ck = *(const uint4*)(kp);
    cv = *(const uint4*)(kp + CDIM);
  }
  uint4 nk = ck, nv = cv;

  for (int t = tb; t < te; ++t) {
    __syncthreads();
    {
      *(uint4*)(&Ks[jr*AST + sg]) = ck;
      union { uint4 u; __hip_bfloat16 hh[8]; } a0; a0.u = cv;
      #pragma unroll
      for (int e = 0; e < 8; ++e) Vt[(sg + e)*AST + jr] = a0.hh[e];
    }
    if (t + 1 < te) {
      const __hip_bfloat16* kp = qkv + kvbase + (size_t)((t+1)*64 + jr)*(3*CDIM) + CDIM + sg;
      nk = *(const uint4*)(kp);
      nv = *(const uint4*)(kp + CDIM);
    }
    __syncthreads();

    f32x4_t sacc[4];
    __builtin_amdgcn_s_setprio(1);
    #pragma unroll
    for (int tn = 0; tn < 4; ++tn) {
      sacc[tn] = (f32x4_t){0.f,0.f,0.f,0.f};
      bf16x8_t bk0 = *(const bf16x8_t*)(&Ks[(tn*16 + colq)*AST + q8]);
      sacc[tn] = __builtin_amdgcn_mfma_f32_16x16x32_bf16(qa0, bk0, sacc[tn], 0, 0, 0);
      bf16x8_t bk1 = *(const bf16x8_t*)(&Ks[(tn*16 + colq)*AST + 32 + q8]);
      sacc[tn] = __builtin_amdgcn_mfma_f32_16x16x32_bf16(qa1, bk1, sacc[tn], 0, 0, 0);
    }
    __builtin_amdgcn_s_setprio(0);

    float sc[4][4];
    #pragma unroll
    for (int tn = 0; tn < 4; ++tn)
    #pragma unroll
    for (int r = 0; r < 4; ++r) sc[tn][r] = sacc[tn][r] * 0.125f;
    if (t >= 2*qt2) {
      #pragma unroll
      for (int tn = 0; tn < 4; ++tn)
      #pragma unroll
      for (int r = 0; r < 4; ++r) {
        int key = t*64 + tn*16 + colq;
        int row = t0 + wv*16 + quad*4 + r;
        if (key > row) sc[tn][r] = -1e30f;
      }
    }

    float mx[4];
    #pragma unroll
    for (int r = 0; r < 4; ++r) {
      mx[r] = fmaxf(fmaxf(sc[0][r], sc[1][r]), fmaxf(sc[2][r], sc[3][r]));
      #pragma unroll
      for (int off = 8; off; off >>= 1) mx[r] = fmaxf(mx[r], __shfl_xor(mx[r], off));
    }
    bool grow = (mx[0] > mr[0] + 8.f) || (mx[1] > mr[1] + 8.f) ||
                (mx[2] > mr[2] + 8.f) || (mx[3] > mr[3] + 8.f);
    if (__any(grow)) {
      #pragma unroll
      for (int r = 0; r < 4; ++r) {
        float mn = fmaxf(mr[r], mx[r]);
        float al = __expf(mr[r] - mn);
        mr[r] = mn;
        lr[r] *= al;
        #pragma unroll
        for (int tn = 0; tn < 4; ++tn) oacc[tn][r] *= al;
      }
    }
    float psum[4] = {0.f,0.f,0.f,0.f};
    #pragma unroll
    for (int tn = 0; tn < 4; ++tn)
    #pragma unroll
    for (int r = 0; r < 4; ++r) {
      float p = __expf(sc[tn][r] - mr[r]);
      psum[r] += p;
      Ps[wv][(quad*4 + r)*AST + tn*16 + colq] = __float2bfloat16(p);
    }
    #pragma unroll
    for (int r = 0; r < 4; ++r) {
      #pragma unroll
      for (int off = 8; off; off >>= 1) psum[r] += __shfl_xor(psum[r], off);
      lr[r] += psum[r];
    }

    bf16x8_t pa0 = *(const bf16x8_t*)(&Ps[wv][colq*AST + q8]);
    bf16x8_t pa1 = *(const bf16x8_t*)(&Ps[wv][colq*AST + 32 + q8]);
    __builtin_amdgcn_s_setprio(1);
    #pragma unroll
    for (int tn = 0; tn < 4; ++tn) {
      bf16x8_t vb0 = *(const bf16x8_t*)(&Vt[(tn*16 + colq)*AST + q8]);
      oacc[tn] = __builtin_amdgcn_mfma_f32_16x16x32_bf16(pa0, vb0, oacc[tn], 0, 0, 0);
      bf16x8_t vb1 = *(const bf16x8_t*)(&Vt[(tn*16 + colq)*AST + 32 + q8]);
      oacc[tn] = __builtin_amdgcn_mfma_f32_16x16x32_bf16(pa1, vb1, oacc[tn], 0, 0, 0);
    }
    __builtin_amdgcn_s_setprio(0);

    ck = nk; cv = nv;
  }

  if (direct) {
    __hip_bfloat16* yp = y + ((size_t)(b*TSEQ + t0 + wv*16))*CDIM + h*64;
    #pragma unroll
    for (int tn = 0; tn < 4; ++tn)
    #pragma unroll
    for (int r = 0; r < 4; ++r) {
      yp[(size_t)(quad*4 + r)*CDIM + tn*16 + colq] = __float2bfloat16(oacc[tn][r] / lr[r]);
    }
  } else {
    int off = (qt2 >= 12) ? 20 + (qt2-12)*4 : (qt2 >= 8) ? 8 + (qt2-8)*3 : (qt2-4)*2;
    int s = pair*36 + off + ci;
    __hip_bfloat16* op = slot_ptr(pO0, pO1, s);
    #pragma unroll
    for (int tn = 0; tn < 4; ++tn)
    #pragma unroll
    for (int r = 0; r < 4; ++r) {
      op[wv*1024 + tn*256 + r*64 + lane] = __float2bfloat16(oacc[tn][r]);
    }
    if (colq == 0) {
      #pragma unroll
      for (int r = 0; r < 4; ++r)
        ml[(size_t)s*128 + wv*16 + quad*4 + r] = make_float2(mr[r], lr[r]);
    }
  }
}

// ================= launch =================
extern "C" void kernel_launch(void* const* d_in, const int* in_sizes, int n_in,
                              void* d_out, int out_size, void* d_ws, size_t ws_size,
                              hipStream_t stream)
{
  float* out = (float*)d_out;                     // OUTPUT IS FP32
  __hip_bfloat16* ybuf = (__hip_bfloat16*)d_out;  // first 8MB: bf16 attention y scratch
  float* x2d = (float*)d_out;                     // phase-2: x2 fp32 lives in d_out
  char* ws = (char*)d_ws;
  const size_t KB = 1024, MB = 1024*1024;

  if (ws_size < 49*MB) {
    zero32_kernel<<<(out_size + 255)/256, 256, 0, stream>>>(out, out_size);
    return;
  }

  const float* x      = (const float*)d_in[0];
  const float* ln1w   = (const float*)d_in[1];
  const float* ln1b   = (const float*)d_in[2];
  const float* Wattn  = (const float*)d_in[3];
  const float* battn  = (const float*)d_in[4];
  const float* Waproj = (const float*)d_in[5];
  const float* baproj = (const float*)d_in[6];
  const float* ln2w   = (const float*)d_in[7];
  const float* ln2b   = (const float*)d_in[8];
  const float* Wfc    = (const float*)d_in[9];
  const float* bfc    = (const float*)d_in[10];
  const float* Wmproj = (const float*)d_in[11];
  const float* bmproj = (const float*)d_in[12];

  __hip_bfloat16* xn   = (__hip_bfloat16*)(ws + 64*KB);
  char* big            = ws + 64*KB + 8*MB;
  __hip_bfloat16* qkv  = (__hip_bfloat16*)big;
  __hip_bfloat16* gbuf = (__hip_bfloat16*)big;
  __hip_bfloat16* ebuf = (__hip_bfloat16*)(big + 16*MB);
  __hip_bfloat16* hbuf = xn;
  char* creg           = ws + 64*KB + 32*MB;
  __hip_bfloat16* cWattnT  = (__hip_bfloat16*)creg;             // [3072][1024] 6 MB
  __hip_bfloat16* xt       = (__hip_bfloat16*)(creg + 8*MB);    // [4096][1024] 8 MB
  __hip_bfloat16* cWaprojT = (__hip_bfloat16*)creg;             // [1024][1024] 2 MB (after scalmix2)
  __hip_bfloat16* cWfcT    = (__hip_bfloat16*)creg;             // [4096][1024] 8 MB (phase 2)
  __hip_bfloat16* cWmT     = (__hip_bfloat16*)(creg + 8*MB);    // [1024][4096] 8 MB (phase 2)
  __hip_bfloat16* pO0      = (__hip_bfloat16*)creg;             // 1024 slots x 16KB
  __hip_bfloat16* pO1      = (__hip_bfloat16*)((char*)d_out + 8*MB);   // 128 slots
  float2* mlbuf            = (float2*)((char*)d_out + 10*MB);          // 1152*128*8B

  // phase-1: W_attn transpose-convert
  convT_kernel<<<dim3(32, 96), 256, 0, stream>>>(Wattn,  cWattnT,  1024, 3072);

  // 1. xn = LN1(x)
  ln_kernel<<<NROW, 256, 0, stream>>>(x, ln1w, ln1b, xn);
  // 2. logmap coeffs + xt (fused)
  scalmix1_kernel<<<NROW, 256, 0, stream>>>(xn, xt);
  // 3. qkv = xt @ W_attn + b_attn  (128x128, 3-buf, 3 blocks/CU)
  gemmT_kernel<128,128,3,0><<<dim3(32, 24), 256, 0, stream>>>(
      xt, 1024, cWattnT, 1024, battn, nullptr, qkv, 3072, 1024);
  // 4. attention (128 q-rows/block, KV-split) -> ybuf (qt2<4) + partials
  attn_kernel<<<dim3(40, BDIM*HNUM), 512, 0, stream>>>(qkv, ybuf, pO0, pO1, mlbuf);
  // 5. expmap coeffs + e, with inline partial-combine
  scalmix2_kernel<<<NROW, 256, 0, stream>>>(xn, ybuf, pO0, pO1, mlbuf, ebuf);
  // 6. W_aproj convert (partials dead now); x2 = x + e @ W_aproj + b_aproj -> d_out
  convT_kernel<<<dim3(32, 32), 256, 0, stream>>>(Waproj, cWaprojT, 1024, 1024);
  gemmT_kernel<128,128,4,1><<<dim3(32, 8), 256, 0, stream>>>(
      ebuf, 1024, cWaprojT, 1024, baproj, x, x2d, 1024, 1024);
  // phase-2 conversions (one launch)
  convT2_kernel<<<8192, 256, 0, stream>>>(Wfc, cWfcT, Wmproj, cWmT);
  // 7. hbuf = LN2(x2)
  ln_kernel<<<NROW, 256, 0, stream>>>(x2d, ln2w, ln2b, hbuf);
  // 8/9. MLP in 2 hidden-chunks of 2048; fp32 accumulate in d_out
  for (int c = 0; c < 2; ++c) {
    gemmT_kernel<128,128,4,2><<<dim3(32, 16), 256, 0, stream>>>(
        hbuf, 1024, cWfcT + (size_t)c*2048*1024, 1024, bfc + 2048*c, nullptr, gbuf,
        2048, 1024);
    const __hip_bfloat16* Bc = cWmT + 2048*c;
    if (c == 0) {
      gemmT_kernel<128,128,4,1><<<dim3(32, 8), 256, 0, stream>>>(
          gbuf, 2048, Bc, 4096, bmproj, x2d, x2d, 1024, 2048);
    } else {
      gemmT_kernel<128,128,4,7><<<dim3(32, 8), 256, 0, stream>>>(
          gbuf, 2048, Bc, 4096, nullptr, x2d, out, 1024, 2048);
    }
  }
}

// Round 10
// 440.036 us; speedup vs baseline: 1.0721x; 1.0721x over previous
//
#include <hip/hip_runtime.h>
#include <hip/hip_bf16.h>
#include <math.h>

#define BDIM 2
#define TSEQ 2048
#define CDIM 1024
#define HNUM 16
#define NROW (BDIM*TSEQ)
#define AST 88   // attn LDS row stride

typedef __attribute__((ext_vector_type(8))) short bf16x8_t;
typedef __attribute__((ext_vector_type(4))) float f32x4_t;

__device__ inline float bf2f(__hip_bfloat16 h) { return __bfloat162float(h); }

__device__ inline void unpack8(uint4 u, float* f) {
  unsigned v[4] = {u.x, u.y, u.z, u.w};
  #pragma unroll
  for (int i = 0; i < 4; ++i) {
    union { unsigned u2; float f2; } a, b;
    a.u2 = v[i] << 16;
    b.u2 = v[i] & 0xffff0000u;
    f[2*i]   = a.f2;
    f[2*i+1] = b.f2;
  }
}

// async global->LDS, 16B per lane; LDS dest = uniform base + lane*16
__device__ inline void gload16(const void* g, void* l) {
  __builtin_amdgcn_global_load_lds(
      (const __attribute__((address_space(1))) void*)g,
      (__attribute__((address_space(3))) void*)l, 16, 0, 0);
}

template<int N> __device__ inline void waitcnt_vm() {
  asm volatile("s_waitcnt vmcnt(%0)" :: "i"(N) : "memory");
}

__global__ __launch_bounds__(256) void zero32_kernel(float* p, int n) {
  int i = blockIdx.x * 256 + threadIdx.x;
  if (i < n) p[i] = 0.f;
}

// fp32 [K][N] -> bf16 [N][K] transpose-convert via LDS tile
__global__ __launch_bounds__(256) void convT_kernel(const float* __restrict__ src,
    __hip_bfloat16* __restrict__ dst, int K, int N)
{
  __shared__ float tile[32][33];
  const int k0 = blockIdx.x * 32, n0 = blockIdx.y * 32;
  const int tr  = threadIdx.x >> 3;        // 0..31
  const int tc4 = (threadIdx.x & 7) * 4;   // 0,4,..,28
  float4 v = *(const float4*)(src + (size_t)(k0 + tr) * N + n0 + tc4);
  tile[tr][tc4+0] = v.x; tile[tr][tc4+1] = v.y;
  tile[tr][tc4+2] = v.z; tile[tr][tc4+3] = v.w;
  __syncthreads();
  union { ushort4 u; __hip_bfloat16 h[4]; } o;
  #pragma unroll
  for (int j = 0; j < 4; ++j) o.h[j] = __float2bfloat16(tile[tc4+j][tr]);
  *(ushort4*)(dst + (size_t)(n0 + tr) * K + k0 + tc4) = o.u;
}

__device__ inline void blk_reduce3(float& a, float& b, float& c, float* red) {
  const int lane = threadIdx.x & 63, wv = threadIdx.x >> 6;
  #pragma unroll
  for (int off = 32; off; off >>= 1) {
    a += __shfl_xor(a, off); b += __shfl_xor(b, off); c += __shfl_xor(c, off);
  }
  if (lane == 0) { red[wv] = a; red[4+wv] = b; red[8+wv] = c; }
  __syncthreads();
  a = red[0]+red[1]+red[2]+red[3];
  b = red[4]+red[5]+red[6]+red[7];
  c = red[8]+red[9]+red[10]+red[11];
}

// ---------------- LayerNorm: fp32 in, fp32 w/b, bf16 out ----------------
__global__ __launch_bounds__(256) void ln_kernel(const float* __restrict__ x,
    const float* __restrict__ w, const float* __restrict__ b,
    __hip_bfloat16* __restrict__ out)
{
  const int row = blockIdx.x;
  const size_t base = (size_t)row * CDIM;
  const int lane = threadIdx.x & 63, wv = threadIdx.x >> 6;
  float v[4]; float s = 0.f, s2 = 0.f;
  #pragma unroll
  for (int k = 0; k < 4; ++k) {
    int d = threadIdx.x + k*256;
    float xe = x[base + d];
    v[k] = xe; s += xe; s2 += xe*xe;
  }
  __shared__ float red[8];
  #pragma unroll
  for (int off = 32; off; off >>= 1) { s += __shfl_xor(s, off); s2 += __shfl_xor(s2, off); }
  if (lane == 0) { red[wv] = s; red[4+wv] = s2; }
  __syncthreads();
  s  = red[0]+red[1]+red[2]+red[3];
  s2 = red[4]+red[5]+red[6]+red[7];
  float mu = s * (1.0f/CDIM);
  float var = s2 * (1.0f/CDIM) - mu*mu;
  float rstd = rsqrtf(fmaxf(var, 0.f) + 1e-5f);
  #pragma unroll
  for (int k = 0; k < 4; ++k) {
    int d = threadIdx.x + k*256;
    out[base + d] = __float2bfloat16((v[k]-mu)*rstd*w[d] + b[d]);
  }
}

// ---------------- scalmix1: logmap coeffs + xt[r] = P*xn[r] + Q*xn[r-1] ----------------
__global__ __launch_bounds__(256) void scalmix1_kernel(const __hip_bfloat16* __restrict__ xn,
                                                       __hip_bfloat16* __restrict__ xt)
{
  const int row = blockIdx.x;
  const bool has = (row & (TSEQ-1)) != 0;
  const __hip_bfloat16* u  = xn + (size_t)row * CDIM;
  const __hip_bfloat16* xp = xn + (size_t)(has ? row-1 : row) * CDIM;
  float ue[4], xe[4];
  float sxx = 0.f, suu = 0.f, sxu = 0.f;
  #pragma unroll
  for (int k = 0; k < 4; ++k) {
    int d = threadIdx.x + k*256;
    ue[k] = bf2f(u[d]);
    xe[k] = has ? bf2f(xp[d]) : 0.f;
    sxx += xe[k]*xe[k]; suu += ue[k]*ue[k]; sxu += xe[k]*ue[k];
  }
  __shared__ float red[12];
  blk_reduce3(sxx, suu, sxu, red);
  float den = 1.f - 2.f*sxu + sxx*suu;
  float inv = 1.f / fmaxf(den, 1e-30f);
  float cb = 1.f - sxx;
  float ca = 1.f - 2.f*sxu + suu;
  float mm = inv*inv*(cb*cb*suu - 2.f*ca*cb*sxu + ca*ca*sxx);
  float mn = sqrtf(fmaxf(mm, 0.f));
  float arg = fminf(sqrtf(mn), 0.999f);
  float fac = (1.f + sxx) * atanhf(arg) / fmaxf(mn, 1e-30f);
  float P = fac*cb*inv;
  float Q = has ? -fac*ca*inv : 0.f;
  #pragma unroll
  for (int k = 0; k < 4; ++k) {
    int d = threadIdx.x + k*256;
    xt[(size_t)row*CDIM + d] = __float2bfloat16(P*ue[k] + Q*xe[k]);
  }
}

// ---------------- scalmix2: expmap coeffs + e[r] = S*y[r] + R*xn[r-1] ----------------
__global__ __launch_bounds__(256) void scalmix2_kernel(const __hip_bfloat16* __restrict__ xn,
                                                       const __hip_bfloat16* __restrict__ y,
                                                       __hip_bfloat16* __restrict__ e)
{
  const int row = blockIdx.x;
  const bool has = (row & (TSEQ-1)) != 0;
  const __hip_bfloat16* xp = xn + (size_t)(has ? row-1 : row) * CDIM;
  const __hip_bfloat16* vr = y + (size_t)row * CDIM;
  float ve[4], xe[4];
  float sxx = 0.f, svv = 0.f, sxv = 0.f;
  #pragma unroll
  for (int k = 0; k < 4; ++k) {
    int d = threadIdx.x + k*256;
    ve[k] = bf2f(vr[d]);
    xe[k] = has ? bf2f(xp[d]) : 0.f;
    sxx += xe[k]*xe[k]; svv += ve[k]*ve[k]; sxv += xe[k]*ve[k];
  }
  __shared__ float red[12];
  blk_reduce3(sxx, svv, sxv, red);
  float lam = 2.f / (1.f + sxx);
  float vn  = sqrtf(fmaxf(svv, 1e-30f));
  float th  = tanhf(vn * sqrtf(0.5f*lam));
  float s   = th / vn;
  float yn2 = th*th;
  float ip  = s * sxv;
  float den = 1.f + 2.f*ip + sxx*yn2;
  float inv = 1.f / fmaxf(den, 1e-30f);
  float S = (1.f - sxx)*s*inv;
  float R = has ? (1.f + 2.f*ip + yn2)*inv : 0.f;
  #pragma unroll
  for (int k = 0; k < 4; ++k) {
    int d = threadIdx.x + k*256;
    e[(size_t)row*CDIM + d] = __float2bfloat16(S*ve[k] + R*xe[k]);
  }
}

// ---------------- MFMA GEMM: 3-buffer counted-vmcnt pipeline ----------------
// A [M][K], Bt [N][K], both bf16. Body: wait vmcnt(L) -> s_barrier -> stage(t+2) -> compute(t).
// Loads never drained to 0 inside the loop (T4).
// MODE 0: bf16 out = acc + bias
// MODE 1: f32  out = acc + bias + res   (in-place ok)
// MODE 2: bf16 out = gelu(acc + bias)
// MODE 7: f32  out = acc + res          (in-place ok)
template<int BM, int BN, int MODE>
__global__ __launch_bounds__(256) void gemmT_kernel(
    const __hip_bfloat16* __restrict__ A, int lda,
    const __hip_bfloat16* __restrict__ Bt, int ldb,
    const float* __restrict__ bias,
    const float* __restrict__ res,
    void* __restrict__ outp,
    int N, int K)
{
  __shared__ __align__(16) __hip_bfloat16 As[3][BM*32];
  __shared__ __align__(16) __hip_bfloat16 Bs[3][BN*32];
  const int bm = blockIdx.x, bn = blockIdx.y;
  const int tid = threadIdx.x, lane = tid & 63, wv = tid >> 6;
  constexpr int FM = BM/32, FN = BN/32;
  const int wm = (wv >> 1) * (BM/2), wn = (wv & 1) * (BN/2);
  f32x4_t acc[FM][FN];
  #pragma unroll
  for (int m = 0; m < FM; ++m)
    #pragma unroll
    for (int n = 0; n < FN; ++n) acc[m][n] = (f32x4_t){0.f,0.f,0.f,0.f};

  const int fr = lane & 15, quad = lane >> 4, q8 = quad * 8;
  const int srow = lane >> 2, scol = (lane & 3) * 8;
  constexpr int SA = BM/16, SB = BN/16;
  constexpr int L = SA/4 + SB/4;   // per-wave loads per tile
  const __hip_bfloat16* Ag = A  + (size_t)(bm*BM + srow)*lda + scol;
  const __hip_bfloat16* Bg = Bt + (size_t)(bn*BN + srow)*ldb + scol;

  const int nk = K/32;

  // prologue: stage tiles 0,1 into buffers 0,1
  #pragma unroll
  for (int i = 0; i < SA/4; ++i) {
    int s = wv*(SA/4) + i;
    gload16(Ag + (size_t)(s*16)*lda, &As[0][s*512]);
  }
  #pragma unroll
  for (int i = 0; i < SB/4; ++i) {
    int s = wv*(SB/4) + i;
    gload16(Bg + (size_t)(s*16)*ldb, &Bs[0][s*512]);
  }
  #pragma unroll
  for (int i = 0; i < SA/4; ++i) {
    int s = wv*(SA/4) + i;
    gload16(Ag + (size_t)(s*16)*lda + 32, &As[1][s*512]);
  }
  #pragma unroll
  for (int i = 0; i < SB/4; ++i) {
    int s = wv*(SB/4) + i;
    gload16(Bg + (size_t)(s*16)*ldb + 32, &Bs[1][s*512]);
  }

  int b0 = 0, b1 = 1, b2 = 2;
  for (int t = 0; t < nk; ++t) {
    if (t + 1 < nk) waitcnt_vm<L>(); else waitcnt_vm<0>();
    __builtin_amdgcn_s_barrier();
    __builtin_amdgcn_sched_barrier(0);
    if (t + 2 < nk) {
      const int k0 = (t+2)*32;
      #pragma unroll
      for (int i = 0; i < SA/4; ++i) {
        int s = wv*(SA/4) + i;
        gload16(Ag + (size_t)(s*16)*lda + k0, &As[b2][s*512]);
      }
      #pragma unroll
      for (int i = 0; i < SB/4; ++i) {
        int s = wv*(SB/4) + i;
        gload16(Bg + (size_t)(s*16)*ldb + k0, &Bs[b2][s*512]);
      }
    }
    bf16x8_t af[FM], bfr[FN];
    #pragma unroll
    for (int m = 0; m < FM; ++m) af[m]  = *(const bf16x8_t*)&As[b0][(wm + m*16 + fr)*32 + q8];
    #pragma unroll
    for (int n = 0; n < FN; ++n) bfr[n] = *(const bf16x8_t*)&Bs[b0][(wn + n*16 + fr)*32 + q8];
    __builtin_amdgcn_s_setprio(1);
    #pragma unroll
    for (int m = 0; m < FM; ++m)
      #pragma unroll
      for (int n = 0; n < FN; ++n)
        acc[m][n] = __builtin_amdgcn_mfma_f32_16x16x32_bf16(af[m], bfr[n], acc[m][n], 0, 0, 0);
    __builtin_amdgcn_s_setprio(0);
    int tmp = b0; b0 = b1; b1 = b2; b2 = tmp;
  }

  #pragma unroll
  for (int m = 0; m < FM; ++m)
  #pragma unroll
  for (int n = 0; n < FN; ++n)
  #pragma unroll
  for (int r = 0; r < 4; ++r) {
    int row = bm*BM + wm + m*16 + quad*4 + r;
    int col = bn*BN + wn + n*16 + fr;
    size_t idx = (size_t)row * N + col;
    float v = acc[m][n][r];
    if (MODE == 0) {
      v += bias[col];
      ((__hip_bfloat16*)outp)[idx] = __float2bfloat16(v);
    } else if (MODE == 1) {
      v += bias[col] + res[idx];
      ((float*)outp)[idx] = v;
    } else if (MODE == 2) {
      v += bias[col];
      v = 0.5f * v * (1.0f + erff(v * 0.70710678118654752f));
      ((__hip_bfloat16*)outp)[idx] = __float2bfloat16(v);
    } else {
      v += res[idx];
      ((float*)outp)[idx] = v;
    }
  }
}

// ---------------- partial-slot pointer helper ----------------
__device__ inline __hip_bfloat16* slot_ptr(__hip_bfloat16* p0, __hip_bfloat16* p1, int s) {
  return (s < 2048) ? p0 + (size_t)s*4096 : p1 + (size_t)(s-2048)*4096;
}

// ---------------- MFMA flash attention, KV-split + prefetch + defer-max ----------------
__global__ __launch_bounds__(256) void attn_kernel(const __hip_bfloat16* __restrict__ qkv,
                                                   __hip_bfloat16* __restrict__ y,
                                                   __hip_bfloat16* __restrict__ pO0,
                                                   __hip_bfloat16* __restrict__ pO1,
                                                   float2* __restrict__ ml)
{
  const int wid = blockIdx.x;
  int qt, ci;
  if (wid < 32)      { qt = 31 - (wid >> 2); ci = wid & 3; }
  else if (wid < 56) { int w = wid - 32; qt = 23 - w/3; ci = w - (23 - qt)*3; }
  else if (wid < 72) { int w = wid - 56; qt = 15 - (w >> 1); ci = w & 1; }
  else               { qt = 79 - wid; ci = 0; }
  const int tb = ci * 8;
  const int te = min(tb + 8, qt + 1);
  const bool direct = (qt < 8);

  const int pair = blockIdx.y;
  const int b  = pair >> 4;
  const int h  = pair & 15;
  const int tid = threadIdx.x;
  const int lane = tid & 63;
  const int wv = tid >> 6;
  const int t0 = qt * 64;

  __shared__ __align__(16) __hip_bfloat16 Ks[64*AST];     // K tile [key][d]
  __shared__ __align__(16) __hip_bfloat16 Vt[64*AST];     // V tile transposed [d][key]
  __shared__ __align__(16) __hip_bfloat16 Ps[4][16*AST];  // per-wave P strip [q][key]

  const int colq = lane & 15, quad = lane >> 4;
  const int q8 = quad * 8;

  const __hip_bfloat16* qp = qkv + ((size_t)(b*TSEQ + t0 + wv*16 + colq))*(3*CDIM) + h*64;
  const bf16x8_t qa0 = *(const bf16x8_t*)(qp + q8);
  const bf16x8_t qa1 = *(const bf16x8_t*)(qp + 32 + q8);

  f32x4_t oacc[4];
  #pragma unroll
  for (int tn = 0; tn < 4; ++tn) oacc[tn] = (f32x4_t){0.f,0.f,0.f,0.f};
  float mr[4] = {-1e30f,-1e30f,-1e30f,-1e30f};
  float lr[4] = {0.f,0.f,0.f,0.f};

  const int jr = tid >> 2;
  const int sg = (tid & 3) * 16;
  const size_t kvbase = ((size_t)(b*TSEQ))*(3*CDIM) + h*64;

  uint4 ck0, ck1, cv0, cv1;
  {
    const __hip_bfloat16* kp = qkv + kvbase + (size_t)(tb*64 + jr)*(3*CDIM) + CDIM + sg;
    ck0 = *(const uint4*)(kp);
    ck1 = *(const uint4*)(kp + 8);
    cv0 = *(const uint4*)(kp + CDIM);
    cv1 = *(const uint4*)(kp + CDIM + 8);
  }
  uint4 nk0 = ck0, nk1 = ck1, nv0 = cv0, nv1 = cv1;

  for (int t = tb; t < te; ++t) {
    __syncthreads();
    {
      *(uint4*)(&Ks[jr*AST + sg])     = ck0;
      *(uint4*)(&Ks[jr*AST + sg + 8]) = ck1;
      union { uint4 u; __hip_bfloat16 hh[8]; } a0, a1;
      a0.u = cv0; a1.u = cv1;
      #pragma unroll
      for (int e = 0; e < 8; ++e) Vt[(sg + e)*AST + jr]     = a0.hh[e];
      #pragma unroll
      for (int e = 0; e < 8; ++e) Vt[(sg + 8 + e)*AST + jr] = a1.hh[e];
    }
    if (t + 1 < te) {
      const __hip_bfloat16* kp = qkv + kvbase + (size_t)((t+1)*64 + jr)*(3*CDIM) + CDIM + sg;
      nk0 = *(const uint4*)(kp);
      nk1 = *(const uint4*)(kp + 8);
      nv0 = *(const uint4*)(kp + CDIM);
      nv1 = *(const uint4*)(kp + CDIM + 8);
    }
    __syncthreads();

    f32x4_t sacc[4];
    __builtin_amdgcn_s_setprio(1);
    #pragma unroll
    for (int tn = 0; tn < 4; ++tn) {
      sacc[tn] = (f32x4_t){0.f,0.f,0.f,0.f};
      bf16x8_t bk0 = *(const bf16x8_t*)(&Ks[(tn*16 + colq)*AST + q8]);
      sacc[tn] = __builtin_amdgcn_mfma_f32_16x16x32_bf16(qa0, bk0, sacc[tn], 0, 0, 0);
      bf16x8_t bk1 = *(const bf16x8_t*)(&Ks[(tn*16 + colq)*AST + 32 + q8]);
      sacc[tn] = __builtin_amdgcn_mfma_f32_16x16x32_bf16(qa1, bk1, sacc[tn], 0, 0, 0);
    }
    __builtin_amdgcn_s_setprio(0);

    float sc[4][4];
    #pragma unroll
    for (int tn = 0; tn < 4; ++tn)
    #pragma unroll
    for (int r = 0; r < 4; ++r) sc[tn][r] = sacc[tn][r] * 0.125f;
    if (t == qt) {
      #pragma unroll
      for (int tn = 0; tn < 4; ++tn)
      #pragma unroll
      for (int r = 0; r < 4; ++r) {
        int key = t*64 + tn*16 + colq;
        int row = t0 + wv*16 + quad*4 + r;
        if (key > row) sc[tn][r] = -1e30f;
      }
    }

    float mx[4];
    #pragma unroll
    for (int r = 0; r < 4; ++r) {
      mx[r] = fmaxf(fmaxf(sc[0][r], sc[1][r]), fmaxf(sc[2][r], sc[3][r]));
      #pragma unroll
      for (int off = 8; off; off >>= 1) mx[r] = fmaxf(mx[r], __shfl_xor(mx[r], off));
    }
    // defer-max (T13): only rescale when some row's max grew by > 8
    bool grow = (mx[0] > mr[0] + 8.f) || (mx[1] > mr[1] + 8.f) ||
                (mx[2] > mr[2] + 8.f) || (mx[3] > mr[3] + 8.f);
    if (__any(grow)) {
      #pragma unroll
      for (int r = 0; r < 4; ++r) {
        float mn = fmaxf(mr[r], mx[r]);
        float al = __expf(mr[r] - mn);
        mr[r] = mn;
        lr[r] *= al;
        #pragma unroll
        for (int tn = 0; tn < 4; ++tn) oacc[tn][r] *= al;
      }
    }
    float psum[4] = {0.f,0.f,0.f,0.f};
    #pragma unroll
    for (int tn = 0; tn < 4; ++tn)
    #pragma unroll
    for (int r = 0; r < 4; ++r) {
      float p = __expf(sc[tn][r] - mr[r]);
      psum[r] += p;
      Ps[wv][(quad*4 + r)*AST + tn*16 + colq] = __float2bfloat16(p);
    }
    #pragma unroll
    for (int r = 0; r < 4; ++r) {
      #pragma unroll
      for (int off = 8; off; off >>= 1) psum[r] += __shfl_xor(psum[r], off);
      lr[r] += psum[r];
    }

    bf16x8_t pa0 = *(const bf16x8_t*)(&Ps[wv][colq*AST + q8]);
    bf16x8_t pa1 = *(const bf16x8_t*)(&Ps[wv][colq*AST + 32 + q8]);
    __builtin_amdgcn_s_setprio(1);
    #pragma unroll
    for (int tn = 0; tn < 4; ++tn) {
      bf16x8_t vb0 = *(const bf16x8_t*)(&Vt[(tn*16 + colq)*AST + q8]);
      oacc[tn] = __builtin_amdgcn_mfma_f32_16x16x32_bf16(pa0, vb0, oacc[tn], 0, 0, 0);
      bf16x8_t vb1 = *(const bf16x8_t*)(&Vt[(tn*16 + colq)*AST + 32 + q8]);
      oacc[tn] = __builtin_amdgcn_mfma_f32_16x16x32_bf16(pa1, vb1, oacc[tn], 0, 0, 0);
    }
    __builtin_amdgcn_s_setprio(0);

    ck0 = nk0; ck1 = nk1; cv0 = nv0; cv1 = nv1;
  }

  if (direct) {
    __hip_bfloat16* yp = y + ((size_t)(b*TSEQ + t0 + wv*16))*CDIM + h*64;
    #pragma unroll
    for (int tn = 0; tn < 4; ++tn)
    #pragma unroll
    for (int r = 0; r < 4; ++r) {
      yp[(size_t)(quad*4 + r)*CDIM + tn*16 + colq] = __float2bfloat16(oacc[tn][r] / lr[r]);
    }
  } else {
    int off = (qt >= 24) ? 40 + (qt-24)*4 : (qt >= 16) ? 16 + (qt-16)*3 : (qt-8)*2;
    int s = pair*72 + off + ci;
    __hip_bfloat16* op = slot_ptr(pO0, pO1, s);
    #pragma unroll
    for (int tn = 0; tn < 4; ++tn)
    #pragma unroll
    for (int r = 0; r < 4; ++r) {
      op[wv*1024 + tn*256 + r*64 + lane] = __float2bfloat16(oacc[tn][r]);
    }
    if (colq == 0) {
      #pragma unroll
      for (int r = 0; r < 4; ++r)
        ml[(size_t)s*64 + wv*16 + quad*4 + r] = make_float2(mr[r], lr[r]);
    }
  }
}

// ---------------- combine partials for qt>=8 ----------------
__global__ __launch_bounds__(256) void combine_kernel(__hip_bfloat16* __restrict__ pO0,
                                                      __hip_bfloat16* __restrict__ pO1,
                                                      const float2* __restrict__ ml,
                                                      __hip_bfloat16* __restrict__ y)
{
  const int qt = 8 + blockIdx.x;
  const int pair = blockIdx.y;
  const int b = pair >> 4, h = pair & 15;
  const int nch = (qt >= 24) ? 4 : (qt >= 16) ? 3 : 2;
  const int off = (qt >= 24) ? 40 + (qt-24)*4 : (qt >= 16) ? 16 + (qt-16)*3 : (qt-8)*2;
  const int s0 = pair*72 + off;
  const int tid = threadIdx.x;
  const int q = tid >> 2;
  const int dseg = (tid & 3) * 16;

  float mi[4], li[4];
  float M = -1e30f;
  #pragma unroll
  for (int i = 0; i < 4; ++i) {
    if (i < nch) {
      float2 t = ml[(size_t)(s0+i)*64 + q];
      mi[i] = t.x; li[i] = t.y;
      M = fmaxf(M, t.x);
    }
  }
  float w[4]; float denom = 0.f;
  #pragma unroll
  for (int i = 0; i < 4; ++i) {
    if (i < nch) { w[i] = __expf(mi[i] - M); denom += li[i]*w[i]; }
  }
  const int base = (q >> 4)*1024 + (dseg >> 4)*256 + (q & 3)*64 + ((q >> 2) & 3)*16;
  float acc[16];
  #pragma unroll
  for (int j = 0; j < 16; ++j) acc[j] = 0.f;
  #pragma unroll
  for (int i = 0; i < 4; ++i) {
    if (i < nch) {
      const __hip_bfloat16* op = slot_ptr(pO0, pO1, s0+i) + base;
      uint4 u0 = *(const uint4*)(op);
      uint4 u1 = *(const uint4*)(op + 8);
      float f[16];
      unpack8(u0, f); unpack8(u1, f+8);
      #pragma unroll
      for (int j = 0; j < 16; ++j) acc[j] += w[i]*f[j];
    }
  }
  float inv = 1.f / denom;
  union { uint4 u[2]; __hip_bfloat16 hh[16]; } o;
  #pragma unroll
  for (int j = 0; j < 16; ++j) o.hh[j] = __float2bfloat16(acc[j]*inv);
  __hip_bfloat16* yp = y + ((size_t)(b*TSEQ + qt*64 + q))*CDIM + h*64 + dseg;
  *(uint4*)(yp) = o.u[0];
  *(uint4*)(yp + 8) = o.u[1];
}

// ================= launch =================
extern "C" void kernel_launch(void* const* d_in, const int* in_sizes, int n_in,
                              void* d_out, int out_size, void* d_ws, size_t ws_size,
                              hipStream_t stream)
{
  float* out = (float*)d_out;                     // OUTPUT IS FP32
  __hip_bfloat16* ybuf = (__hip_bfloat16*)d_out;  // first 8MB: bf16 attention y scratch
  float* x2d = (float*)d_out;                     // phase-2: x2 fp32 lives in d_out
  char* ws = (char*)d_ws;
  const size_t KB = 1024, MB = 1024*1024;

  if (ws_size < 49*MB) {
    zero32_kernel<<<(out_size + 255)/256, 256, 0, stream>>>(out, out_size);
    return;
  }

  const float* x      = (const float*)d_in[0];
  const float* ln1w   = (const float*)d_in[1];
  const float* ln1b   = (const float*)d_in[2];
  const float* Wattn  = (const float*)d_in[3];
  const float* battn  = (const float*)d_in[4];
  const float* Waproj = (const float*)d_in[5];
  const float* baproj = (const float*)d_in[6];
  const float* ln2w   = (const float*)d_in[7];
  const float* ln2b   = (const float*)d_in[8];
  const float* Wfc    = (const float*)d_in[9];
  const float* bfc    = (const float*)d_in[10];
  const float* Wmproj = (const float*)d_in[11];
  const float* bmproj = (const float*)d_in[12];

  __hip_bfloat16* xn   = (__hip_bfloat16*)(ws + 64*KB);
  char* big            = ws + 64*KB + 8*MB;
  __hip_bfloat16* qkv  = (__hip_bfloat16*)big;
  __hip_bfloat16* gbuf = (__hip_bfloat16*)big;
  __hip_bfloat16* ebuf = (__hip_bfloat16*)(big + 16*MB);
  __hip_bfloat16* hbuf = xn;
  char* creg           = ws + 64*KB + 32*MB;
  __hip_bfloat16* cWattnT  = (__hip_bfloat16*)creg;             // [3072][1024] 6 MB
  __hip_bfloat16* xt       = (__hip_bfloat16*)(creg + 8*MB);    // [4096][1024] 8 MB
  __hip_bfloat16* cWaprojT = (__hip_bfloat16*)creg;             // [1024][1024] 2 MB (after combine)
  __hip_bfloat16* cWfcT    = (__hip_bfloat16*)creg;             // [4096][1024] 8 MB (phase 2)
  __hip_bfloat16* cWmT     = (__hip_bfloat16*)(creg + 8*MB);    // [1024][4096] 8 MB (phase 2)
  __hip_bfloat16* pO0      = (__hip_bfloat16*)creg;             // 2048 slots x 8KB
  __hip_bfloat16* pO1      = (__hip_bfloat16*)((char*)d_out + 8*MB);   // 256 slots
  float2* mlbuf            = (float2*)((char*)d_out + 10*MB);          // 2304*64*8B

  // phase-1: W_attn transpose-convert
  convT_kernel<<<dim3(32, 96), 256, 0, stream>>>(Wattn,  cWattnT,  1024, 3072);

  // 1. xn = LN1(x)
  ln_kernel<<<NROW, 256, 0, stream>>>(x, ln1w, ln1b, xn);
  // 2. logmap coeffs + xt (fused)
  scalmix1_kernel<<<NROW, 256, 0, stream>>>(xn, xt);
  // 3. qkv = xt @ W_attn + b_attn
  gemmT_kernel<128,128,0><<<dim3(32, 24), 256, 0, stream>>>(
      xt, 1024, cWattnT, 1024, battn, nullptr, qkv, 3072, 1024);
  // 4. attention (KV-split) -> ybuf + partials; combine
  attn_kernel<<<dim3(80, BDIM*HNUM), 256, 0, stream>>>(qkv, ybuf, pO0, pO1, mlbuf);
  combine_kernel<<<dim3(24, BDIM*HNUM), 256, 0, stream>>>(pO0, pO1, mlbuf, ybuf);
  // 5. W_aproj convert (partials dead); expmap coeffs + e (fused)
  convT_kernel<<<dim3(32, 32), 256, 0, stream>>>(Waproj, cWaprojT, 1024, 1024);
  scalmix2_kernel<<<NROW, 256, 0, stream>>>(xn, ybuf, ebuf);
  // 6. x2 = x + e @ W_aproj + b_aproj  -> d_out (ybuf dead)
  gemmT_kernel<64,64,1><<<dim3(64, 16), 256, 0, stream>>>(
      ebuf, 1024, cWaprojT, 1024, baproj, x, x2d, 1024, 1024);
  // phase-2 conversions
  convT_kernel<<<dim3(32, 128), 256, 0, stream>>>(Wfc,    cWfcT, 1024, 4096);
  convT_kernel<<<dim3(128, 32), 256, 0, stream>>>(Wmproj, cWmT,  4096, 1024);
  // 7. hbuf = LN2(x2)
  ln_kernel<<<NROW, 256, 0, stream>>>(x2d, ln2w, ln2b, hbuf);
  // 8/9. MLP in 2 hidden-chunks of 2048; fp32 accumulate in d_out
  for (int c = 0; c < 2; ++c) {
    gemmT_kernel<64,128,2><<<dim3(64, 16), 256, 0, stream>>>(
        hbuf, 1024, cWfcT + (size_t)c*2048*1024, 1024, bfc + 2048*c, nullptr, gbuf,
        2048, 1024);
    const __hip_bfloat16* Bc = cWmT + 2048*c;
    if (c == 0) {
      gemmT_kernel<64,64,1><<<dim3(64, 16), 256, 0, stream>>>(
          gbuf, 2048, Bc, 4096, bmproj, x2d, x2d, 1024, 2048);
    } else {
      gemmT_kernel<64,64,7><<<dim3(64, 16), 256, 0, stream>>>(
          gbuf, 2048, Bc, 4096, nullptr, x2d, out, 1024, 2048);
    }
  }
}